// Round 1
// baseline (226.571 us; speedup 1.0000x reference)
//
#include <hip/hip_runtime.h>
#include <hip/hip_bf16.h>
#include <stdint.h>

typedef __bf16 bf16_t;
typedef bf16_t bf16x8 __attribute__((ext_vector_type(8)));
typedef int i32x4 __attribute__((ext_vector_type(4)));
typedef float f32x4 __attribute__((ext_vector_type(4)));

#define QMAXF 127.0f

// async global->LDS, 16B per lane. LDS dest must be linear in lane order.
__device__ __forceinline__ void gl16(const void* g, void* l) {
  __builtin_amdgcn_global_load_lds(
      (__attribute__((address_space(1))) void*)(g),
      (__attribute__((address_space(3))) void*)(l), 16, 0, 0);
}

// ---------------- amax reduction ----------------
__global__ __launch_bounds__(256) void amax_kernel(const float* __restrict__ p, int n,
                                                   float* __restrict__ dst) {
  const int n4 = n >> 2;
  const int stride = gridDim.x * blockDim.x;
  float m = 0.f;
  for (int i = blockIdx.x * blockDim.x + threadIdx.x; i < n4; i += stride) {
    const f32x4 v = ((const f32x4*)p)[i];
    m = fmaxf(m, fmaxf(fmaxf(fabsf(v[0]), fabsf(v[1])), fmaxf(fabsf(v[2]), fabsf(v[3]))));
  }
#pragma unroll
  for (int d = 1; d < 64; d <<= 1) m = fmaxf(m, __shfl_xor(m, d));
  __shared__ float sm[4];
  if ((threadIdx.x & 63) == 0) sm[threadIdx.x >> 6] = m;
  __syncthreads();
  if (threadIdx.x == 0) {
    float mm = fmaxf(fmaxf(sm[0], sm[1]), fmaxf(sm[2], sm[3]));
    atomicMax((int*)dst, __float_as_int(mm));  // valid: values >= 0
  }
}

// ---------------- int8 quantize (matches jnp: clip(round(x/s),-127,127)) ----------------
__global__ __launch_bounds__(256) void quant_kernel(const float* __restrict__ p, int n,
                                                    const float* __restrict__ amax,
                                                    int8_t* __restrict__ q) {
  const float s = fmaxf(amax[0] / QMAXF, 1e-8f);
  const int n4 = n >> 2;
  const int stride = gridDim.x * blockDim.x;
  for (int i = blockIdx.x * blockDim.x + threadIdx.x; i < n4; i += stride) {
    const f32x4 v = ((const f32x4*)p)[i];
    int r[4];
#pragma unroll
    for (int j = 0; j < 4; j++) {
      float t = rintf(v[j] / s);               // RNE == jnp.round
      t = fminf(127.f, fmaxf(-127.f, t));
      r[j] = (int)t;
    }
    ((uint32_t*)q)[i] = (uint32_t)(r[0] & 0xff) | ((uint32_t)(r[1] & 0xff) << 8) |
                        ((uint32_t)(r[2] & 0xff) << 16) | ((uint32_t)(r[3] & 0xff) << 24);
  }
}

// ---------------- int8 GEMM: out[M,N] = A[M,K] * Bw[N,K]^T, K=1024 ----------------
// MODE 0: dequant+bias, scatter to bf16 Q|K|V [which][BH][T][D]  (N=3072)
// MODE 1: dequant+bias, write fp32 row-major [M,1024]            (N=1024)
template <int MODE>
__global__ __launch_bounds__(256) void gemm_i8_kernel(
    const int8_t* __restrict__ A, const int8_t* __restrict__ Bw,
    const float* __restrict__ amaxA, const float* __restrict__ amaxB,
    const float* __restrict__ bias,
    bf16_t* __restrict__ qkv_out, float* __restrict__ f_out) {
  constexpr int K = 1024;
  __shared__ int8_t As[128 * 64];
  __shared__ int8_t Bs[128 * 64];
  const int tid = threadIdx.x;
  const int lane = tid & 63;
  const int w = tid >> 6, wr = w >> 1, wc = w & 1;
  const int l15 = lane & 15, lg = lane >> 4;
  const int bm = blockIdx.y * 128, bn = blockIdx.x * 128;

  const int sr = tid >> 2;            // staging row 0..63
  const int sc = (tid & 3) * 16;      // staging byte col
  const int8_t* gA = A + (size_t)(bm + sr) * K + sc;
  const int8_t* gB = Bw + (size_t)(bn + sr) * K + sc;
  int8_t* lA = As + tid * 16;
  int8_t* lB = Bs + tid * 16;

  i32x4 acc[4][4] = {};

  for (int k0 = 0; k0 < K; k0 += 64) {
    __syncthreads();
    gl16(gA + k0, lA);
    gl16(gA + 64 * K + k0, lA + 4096);
    gl16(gB + k0, lB);
    gl16(gB + 64 * K + k0, lB + 4096);
    __syncthreads();
    i32x4 aF[4], bF[4];
#pragma unroll
    for (int m = 0; m < 4; m++)
      aF[m] = *(const i32x4*)(As + (wr * 64 + m * 16 + l15) * 64 + lg * 16);
#pragma unroll
    for (int n = 0; n < 4; n++)
      bF[n] = *(const i32x4*)(Bs + (wc * 64 + n * 16 + l15) * 64 + lg * 16);
#pragma unroll
    for (int m = 0; m < 4; m++)
#pragma unroll
      for (int n = 0; n < 4; n++)
        acc[m][n] = __builtin_amdgcn_mfma_i32_16x16x64_i8(aF[m], bF[n], acc[m][n], 0, 0, 0);
  }

  const float sA = fmaxf(amaxA[0] / QMAXF, 1e-8f);
  const float sB = fmaxf(amaxB[0] / QMAXF, 1e-8f);
  const float s = sA * sB;

#pragma unroll
  for (int m = 0; m < 4; m++) {
#pragma unroll
    for (int n = 0; n < 4; n++) {
      const int c = bn + wc * 64 + n * 16 + l15;
      const float bs = bias[c];
#pragma unroll
      for (int reg = 0; reg < 4; reg++) {
        const int r = bm + wr * 64 + m * 16 + lg * 4 + reg;
        const float v = (float)acc[m][n][reg] * s + bs;
        if (MODE == 0) {
          const int which = c >> 10, hd = c & 1023;
          const int b = r >> 11, t = r & 2047;
          qkv_out[(size_t)which * (32u * 2048 * 64) +
                  (size_t)((((b << 4) + (hd >> 6)) * 2048 + t) << 6) + (hd & 63)] = (bf16_t)v;
        } else {
          f_out[(size_t)r * 1024 + c] = v;
        }
      }
    }
  }
}

// ---------------- causal flash attention, bf16 MFMA ----------------
// grid: (bh=32, qt=16); block 256 = 4 waves, wave w owns q rows [qb+32w, qb+32w+32)
__global__ __launch_bounds__(256) void attn_kernel(
    const bf16_t* __restrict__ Qg, const bf16_t* __restrict__ Kg, const bf16_t* __restrict__ Vg,
    float* __restrict__ Out, float* __restrict__ amax_out) {
  const int bh = blockIdx.x;
  const int qt = blockIdx.y;
  const int qb = qt * 128;
  const int tid = threadIdx.x, lane = tid & 63, w = tid >> 6;
  const int l15 = lane & 15, lg = lane >> 4;

  const bf16_t* Qp = Qg + (size_t)bh * 2048 * 64;
  const bf16_t* Kp = Kg + (size_t)bh * 2048 * 64;
  const bf16_t* Vp = Vg + (size_t)bh * 2048 * 64;

  __shared__ bf16_t Ks[64][72];       // [kv][d], pad 72 -> conflict-free b128 frags
  __shared__ bf16_t Vt[64][72];       // [d][kv] transposed
  __shared__ bf16_t Ps[4][32][72];    // per-wave P tile [qrow][kv]

  bf16x8 qf[2][2];
#pragma unroll
  for (int rf = 0; rf < 2; rf++)
#pragma unroll
    for (int ks = 0; ks < 2; ks++)
      qf[rf][ks] = *(const bf16x8*)(Qp + (size_t)(qb + w * 32 + rf * 16 + l15) * 64 + ks * 32 + lg * 8);

  f32x4 acc[2][4] = {};
  float mrow[2][4], lrow[2][4];
#pragma unroll
  for (int rf = 0; rf < 2; rf++)
#pragma unroll
    for (int r = 0; r < 4; r++) { mrow[rf][r] = -1e30f; lrow[rf][r] = 0.f; }

  const int nt = 2 * qt + 2;
  for (int it = 0; it < nt; it++) {
    const int kv0 = it * 64;
    __syncthreads();
    {
      const int row = tid >> 3, d0 = (tid & 7) * 8;
#pragma unroll
      for (int half = 0; half < 2; half++) {
        const int rr = row + half * 32;
        *(bf16x8*)(&Ks[rr][d0]) = *(const bf16x8*)(Kp + (size_t)(kv0 + rr) * 64 + d0);
        bf16x8 vv = *(const bf16x8*)(Vp + (size_t)(kv0 + rr) * 64 + d0);
#pragma unroll
        for (int j = 0; j < 8; j++) Vt[d0 + j][rr] = vv[j];
      }
    }
    __syncthreads();

    bf16x8 kF[4][2];
#pragma unroll
    for (int cf = 0; cf < 4; cf++)
#pragma unroll
      for (int ks = 0; ks < 2; ks++)
        kF[cf][ks] = *(const bf16x8*)(&Ks[cf * 16 + l15][ks * 32 + lg * 8]);

    f32x4 sf[2][4] = {};
#pragma unroll
    for (int rf = 0; rf < 2; rf++)
#pragma unroll
      for (int cf = 0; cf < 4; cf++)
#pragma unroll
        for (int ks = 0; ks < 2; ks++)
          sf[rf][cf] = __builtin_amdgcn_mfma_f32_16x16x32_bf16(qf[rf][ks], kF[cf][ks], sf[rf][cf], 0, 0, 0);

    const bool need_mask = (it >= nt - 2);
#pragma unroll
    for (int rf = 0; rf < 2; rf++) {
#pragma unroll
      for (int reg = 0; reg < 4; reg++) {
        float a[4];
#pragma unroll
        for (int cf = 0; cf < 4; cf++) a[cf] = sf[rf][cf][reg] * 0.125f;
        if (need_mask) {
          const int qrow = qb + w * 32 + rf * 16 + lg * 4 + reg;
#pragma unroll
          for (int cf = 0; cf < 4; cf++)
            if (kv0 + cf * 16 + l15 > qrow) a[cf] = -1e30f;
        }
        float mx = fmaxf(fmaxf(a[0], a[1]), fmaxf(a[2], a[3]));
#pragma unroll
        for (int d = 1; d < 16; d <<= 1) mx = fmaxf(mx, __shfl_xor(mx, d));
        const float mold = mrow[rf][reg];
        const float mnew = fmaxf(mold, mx);
        const float alpha = __expf(mold - mnew);
        float p[4], rs = 0.f;
#pragma unroll
        for (int cf = 0; cf < 4; cf++) { p[cf] = __expf(a[cf] - mnew); rs += p[cf]; }
#pragma unroll
        for (int d = 1; d < 16; d <<= 1) rs += __shfl_xor(rs, d);
        mrow[rf][reg] = mnew;
        lrow[rf][reg] = lrow[rf][reg] * alpha + rs;
#pragma unroll
        for (int cf = 0; cf < 4; cf++) acc[rf][cf][reg] *= alpha;
        const int prow = rf * 16 + lg * 4 + reg;
#pragma unroll
        for (int cf = 0; cf < 4; cf++) Ps[w][prow][cf * 16 + l15] = (bf16_t)p[cf];
      }
    }

    // wave-local LDS visibility for Ps (per-wave buffer, no cross-wave barrier needed)
    asm volatile("s_waitcnt lgkmcnt(0)" ::: "memory");

    bf16x8 pf[2][2], vf[4][2];
#pragma unroll
    for (int rf = 0; rf < 2; rf++)
#pragma unroll
      for (int ks = 0; ks < 2; ks++)
        pf[rf][ks] = *(const bf16x8*)(&Ps[w][rf * 16 + l15][ks * 32 + lg * 8]);
#pragma unroll
    for (int cf = 0; cf < 4; cf++)
#pragma unroll
      for (int ks = 0; ks < 2; ks++)
        vf[cf][ks] = *(const bf16x8*)(&Vt[cf * 16 + l15][ks * 32 + lg * 8]);
#pragma unroll
    for (int rf = 0; rf < 2; rf++)
#pragma unroll
      for (int cf = 0; cf < 4; cf++)
#pragma unroll
        for (int ks = 0; ks < 2; ks++)
          acc[rf][cf] = __builtin_amdgcn_mfma_f32_16x16x32_bf16(pf[rf][ks], vf[cf][ks], acc[rf][cf], 0, 0, 0);
  }

  const int b = bh >> 4, h = bh & 15;
  float am = 0.f;
#pragma unroll
  for (int rf = 0; rf < 2; rf++) {
#pragma unroll
    for (int reg = 0; reg < 4; reg++) {
      const float inv = 1.0f / lrow[rf][reg];
      const int t = qb + w * 32 + rf * 16 + lg * 4 + reg;
#pragma unroll
      for (int cf = 0; cf < 4; cf++) {
        const float v = acc[rf][cf][reg] * inv;
        am = fmaxf(am, fabsf(v));
        Out[(size_t)(b * 2048 + t) * 1024 + h * 64 + cf * 16 + l15] = v;
      }
    }
  }
#pragma unroll
  for (int d = 1; d < 64; d <<= 1) am = fmaxf(am, __shfl_xor(am, d));
  if (lane == 0) atomicMax((int*)amax_out, __float_as_int(am));
}

// ---------------- host ----------------
extern "C" void kernel_launch(void* const* d_in, const int* in_sizes, int n_in,
                              void* d_out, int out_size, void* d_ws, size_t ws_size,
                              hipStream_t stream) {
  const float* x = (const float*)d_in[0];
  const float* Wqkv = (const float*)d_in[1];
  const float* bqkv = (const float*)d_in[2];
  const float* Wproj = (const float*)d_in[3];
  const float* bproj = (const float*)d_in[4];
  float* out = (float*)d_out;

  char* ws = (char*)d_ws;
  float* amax = (float*)ws;                              // 4 floats: x, wqkv, wproj, aout
  int8_t* xq = (int8_t*)(ws + 256);                      // 4 MB
  int8_t* wqq = xq + (size_t)4096 * 1024;                // 3 MB
  int8_t* wpq = wqq + (size_t)3072 * 1024;               // 1 MB
  bf16_t* qkv = (bf16_t*)(ws + 8388864);                 // Q|K|V 3x8 MB bf16 [BH][T][D]
  float* aout = (float*)(ws + 33554688);                 // 16 MB attn out fp32
  int8_t* outq = (int8_t*)(ws + 50331904);               // 4 MB

  hipMemsetAsync(amax, 0, 16, stream);
  amax_kernel<<<512, 256, 0, stream>>>(x, 4194304, amax + 0);
  amax_kernel<<<512, 256, 0, stream>>>(Wqkv, 3145728, amax + 1);
  amax_kernel<<<256, 256, 0, stream>>>(Wproj, 1048576, amax + 2);
  quant_kernel<<<512, 256, 0, stream>>>(x, 4194304, amax + 0, xq);
  quant_kernel<<<512, 256, 0, stream>>>(Wqkv, 3145728, amax + 1, wqq);
  quant_kernel<<<256, 256, 0, stream>>>(Wproj, 1048576, amax + 2, wpq);
  gemm_i8_kernel<0><<<dim3(24, 32), 256, 0, stream>>>(xq, wqq, amax + 0, amax + 1, bqkv, qkv, nullptr);
  attn_kernel<<<dim3(32, 16), 256, 0, stream>>>(qkv, qkv + (size_t)32 * 2048 * 64,
                                                qkv + (size_t)2 * 32 * 2048 * 64, aout, amax + 3);
  quant_kernel<<<512, 256, 0, stream>>>(aout, 4194304, amax + 3, outq);
  gemm_i8_kernel<1><<<dim3(8, 32), 256, 0, stream>>>(outq, wpq, amax + 3, amax + 2, bproj, nullptr, out);
}

// Round 2
// 180.045 us; speedup vs baseline: 1.2584x; 1.2584x over previous
//
#include <hip/hip_runtime.h>
#include <hip/hip_bf16.h>
#include <stdint.h>

typedef __bf16 bf16_t;
typedef bf16_t bf16x8 __attribute__((ext_vector_type(8)));
typedef int i32x4 __attribute__((ext_vector_type(4)));
typedef float f32x4 __attribute__((ext_vector_type(4)));

#define QMAXF 127.0f

// async global->LDS, 16B per lane. LDS dest is wave-uniform base + lane*16 (linear).
__device__ __forceinline__ void gl16(const void* g, void* l) {
  __builtin_amdgcn_global_load_lds(
      (__attribute__((address_space(1))) void*)(g),
      (__attribute__((address_space(3))) void*)(l), 16, 0, 0);
}

// ---------------- amax reduction ----------------
__global__ __launch_bounds__(256) void amax_kernel(const float* __restrict__ p, int n,
                                                   float* __restrict__ dst) {
  const int n4 = n >> 2;
  const int stride = gridDim.x * blockDim.x;
  float m = 0.f;
  for (int i = blockIdx.x * blockDim.x + threadIdx.x; i < n4; i += stride) {
    const f32x4 v = ((const f32x4*)p)[i];
    m = fmaxf(m, fmaxf(fmaxf(fabsf(v[0]), fabsf(v[1])), fmaxf(fabsf(v[2]), fabsf(v[3]))));
  }
#pragma unroll
  for (int d = 1; d < 64; d <<= 1) m = fmaxf(m, __shfl_xor(m, d));
  __shared__ float sm[4];
  if ((threadIdx.x & 63) == 0) sm[threadIdx.x >> 6] = m;
  __syncthreads();
  if (threadIdx.x == 0) {
    float mm = fmaxf(fmaxf(sm[0], sm[1]), fmaxf(sm[2], sm[3]));
    atomicMax((int*)dst, __float_as_int(mm));  // valid: values >= 0
  }
}

// ---------------- int8 quantize (matches jnp: clip(round(x/s),-127,127)) ----------------
__global__ __launch_bounds__(256) void quant_kernel(const float* __restrict__ p, int n,
                                                    const float* __restrict__ amax,
                                                    int8_t* __restrict__ q) {
  const float s = fmaxf(amax[0] / QMAXF, 1e-8f);
  const int n4 = n >> 2;
  const int stride = gridDim.x * blockDim.x;
  for (int i = blockIdx.x * blockDim.x + threadIdx.x; i < n4; i += stride) {
    const f32x4 v = ((const f32x4*)p)[i];
    int r[4];
#pragma unroll
    for (int j = 0; j < 4; j++) {
      float t = rintf(v[j] / s);               // RNE == jnp.round
      t = fminf(127.f, fmaxf(-127.f, t));
      r[j] = (int)t;
    }
    ((uint32_t*)q)[i] = (uint32_t)(r[0] & 0xff) | ((uint32_t)(r[1] & 0xff) << 8) |
                        ((uint32_t)(r[2] & 0xff) << 16) | ((uint32_t)(r[3] & 0xff) << 24);
  }
}

// ---------------- int8 GEMM: out[M,N] = A[M,K] * Bw[N,K]^T, K=1024 ----------------
// MODE 0: dequant+bias; Q,K -> bf16 [which][BH][T][D]; V -> bf16 vtmp [BH][T][D]  (N=3072)
// MODE 1: dequant+bias, write fp32 row-major [M,1024]                             (N=1024)
template <int MODE>
__global__ __launch_bounds__(256) void gemm_i8_kernel(
    const int8_t* __restrict__ A, const int8_t* __restrict__ Bw,
    const float* __restrict__ amaxA, const float* __restrict__ amaxB,
    const float* __restrict__ bias,
    bf16_t* __restrict__ qkv_out, bf16_t* __restrict__ vtmp, float* __restrict__ f_out) {
  constexpr int K = 1024;
  __shared__ int8_t As[128 * 64];
  __shared__ int8_t Bs[128 * 64];
  const int tid = threadIdx.x;
  const int lane = tid & 63;
  const int w = tid >> 6, wr = w >> 1, wc = w & 1;
  const int l15 = lane & 15, lg = lane >> 4;
  const int bm = blockIdx.y * 128, bn = blockIdx.x * 128;

  const int sr = tid >> 2;            // staging row 0..63
  const int sc = (tid & 3) * 16;      // staging byte col
  const int8_t* gA = A + (size_t)(bm + sr) * K + sc;
  const int8_t* gB = Bw + (size_t)(bn + sr) * K + sc;
  int8_t* lA = As + tid * 16;
  int8_t* lB = Bs + tid * 16;

  i32x4 acc[4][4] = {};

  for (int k0 = 0; k0 < K; k0 += 64) {
    __syncthreads();
    gl16(gA + k0, lA);
    gl16(gA + 64 * K + k0, lA + 4096);
    gl16(gB + k0, lB);
    gl16(gB + 64 * K + k0, lB + 4096);
    __syncthreads();
    i32x4 aF[4], bF[4];
#pragma unroll
    for (int m = 0; m < 4; m++)
      aF[m] = *(const i32x4*)(As + (wr * 64 + m * 16 + l15) * 64 + lg * 16);
#pragma unroll
    for (int n = 0; n < 4; n++)
      bF[n] = *(const i32x4*)(Bs + (wc * 64 + n * 16 + l15) * 64 + lg * 16);
#pragma unroll
    for (int m = 0; m < 4; m++)
#pragma unroll
      for (int n = 0; n < 4; n++)
        acc[m][n] = __builtin_amdgcn_mfma_i32_16x16x64_i8(aF[m], bF[n], acc[m][n], 0, 0, 0);
  }

  const float sA = fmaxf(amaxA[0] / QMAXF, 1e-8f);
  const float sB = fmaxf(amaxB[0] / QMAXF, 1e-8f);
  const float s = sA * sB;

#pragma unroll
  for (int m = 0; m < 4; m++) {
#pragma unroll
    for (int n = 0; n < 4; n++) {
      const int c = bn + wc * 64 + n * 16 + l15;
      const float bs = bias[c];
#pragma unroll
      for (int reg = 0; reg < 4; reg++) {
        const int r = bm + wr * 64 + m * 16 + lg * 4 + reg;
        const float v = (float)acc[m][n][reg] * s + bs;
        if (MODE == 0) {
          const int which = c >> 10, hd = c & 1023;
          const int b = r >> 11, t = r & 2047;
          const size_t idx = (size_t)((((b << 4) + (hd >> 6)) * 2048 + t) << 6) + (hd & 63);
          if (which < 2)
            qkv_out[(size_t)which * (32u * 2048 * 64) + idx] = (bf16_t)v;
          else
            vtmp[idx] = (bf16_t)v;
        } else {
          f_out[(size_t)r * 1024 + c] = v;
        }
      }
    }
  }
}

// ---------------- V transpose: [BH][2048][64] -> [BH][64][2048] ----------------
__global__ __launch_bounds__(256) void transpose_v_kernel(const bf16_t* __restrict__ Vin,
                                                          bf16_t* __restrict__ VT) {
  __shared__ bf16_t L[64][72];
  const int bh = blockIdx.y;
  const int t0 = blockIdx.x * 64;
  const int tid = threadIdx.x;
  const bf16_t* src = Vin + ((size_t)bh * 2048 + t0) * 64;
  {
    const int r = tid >> 3, c = (tid & 7) * 8;
    *(bf16x8*)&L[r][c] = *(const bf16x8*)(src + (size_t)r * 64 + c);
    *(bf16x8*)&L[r + 32][c] = *(const bf16x8*)(src + (size_t)(r + 32) * 64 + c);
  }
  __syncthreads();
  bf16_t* dst = VT + (size_t)bh * 64 * 2048 + t0;
  const int d = tid >> 2, c0 = (tid & 3) * 16;
  bf16_t tmp[16];
#pragma unroll
  for (int j = 0; j < 16; j++) tmp[j] = L[c0 + j][d];
  *(bf16x8*)(dst + (size_t)d * 2048 + c0) = *(bf16x8*)(&tmp[0]);
  *(bf16x8*)(dst + (size_t)d * 2048 + c0 + 8) = *(bf16x8*)(&tmp[8]);
}

// ---------------- causal flash attention, bf16 MFMA ----------------
// grid (32 bh, 16 pairs); block 256 = 4 waves x 16 q-rows.
// Block handles q-tiles {y, 31-y} (64 rows each) -> every block does exactly 33 KV-iters.
__global__ __launch_bounds__(256) void attn_kernel(
    const bf16_t* __restrict__ Qg, const bf16_t* __restrict__ Kg, const bf16_t* __restrict__ VTg,
    float* __restrict__ Out, float* __restrict__ amax_out) {
  const int bh = blockIdx.x;
  const int tid = threadIdx.x, lane = tid & 63, w = tid >> 6;
  const int l15 = lane & 15, lg = lane >> 4;
  const int b = bh >> 4, h = bh & 15;

  const bf16_t* Qp = Qg + (size_t)bh * 2048 * 64;
  const char* Kbase = (const char*)(Kg + (size_t)bh * 2048 * 64);
  const char* Vbase = (const char*)(VTg + (size_t)bh * 64 * 2048);

  __shared__ bf16_t Kb[2][4096];     // [64 kv][64 d], linear, XOR-swizzled content
  __shared__ bf16_t Vb[2][4096];     // [64 d][64 kv], linear, XOR-swizzled content
  __shared__ bf16_t Ps[4][16][72];   // per-wave P tile [qrow][kv]

  float am = 0.f;

// stage one 8KB K tile + 8KB V^T tile (pre-swizzled source -> linear LDS dest)
#define STAGE(kv0_, buf_)                                                              \
  {                                                                                    \
    const int _kv0 = (kv0_);                                                           \
    _Pragma("unroll") for (int i_ = 0; i_ < 2; i_++) {                                 \
      const int o_ = ((tid >> 6) << 10) + ((tid & 63) << 4) + (i_ << 12);              \
      const int row_ = o_ >> 7;                                                        \
      const int sbc_ = (o_ & 127) ^ ((row_ & 7) << 4);                                 \
      gl16(Kbase + (size_t)(_kv0 + row_) * 128 + sbc_, (char*)Kb[buf_] + o_);          \
      gl16(Vbase + (size_t)row_ * 4096 + (size_t)_kv0 * 2 + sbc_, (char*)Vb[buf_] + o_); \
    }                                                                                  \
  }

  for (int half = 0; half < 2; ++half) {
    const int tile = half ? (31 - (int)blockIdx.y) : (int)blockIdx.y;
    const int qb = tile * 64 + w * 16;   // this wave's 16 q-rows
    const int nt = tile + 1;

    bf16x8 qf[2];
#pragma unroll
    for (int ks = 0; ks < 2; ks++)
      qf[ks] = *(const bf16x8*)(Qp + (size_t)(qb + l15) * 64 + ks * 32 + lg * 8);

    f32x4 acc[4] = {};
    float mrow[4], lsum[4];
#pragma unroll
    for (int r = 0; r < 4; r++) { mrow[r] = -1e30f; lsum[r] = 0.f; }

    STAGE(0, 0);
    __syncthreads();

    int cur = 0;
    for (int it = 0; it < nt; ++it) {
      if (it + 1 < nt) STAGE((it + 1) * 64, cur ^ 1);   // prefetch flies during compute

      const char* kb = (const char*)Kb[cur];
      const char* vb = (const char*)Vb[cur];

      bf16x8 kF[4][2];
#pragma unroll
      for (int cf = 0; cf < 4; cf++)
#pragma unroll
        for (int ks = 0; ks < 2; ks++) {
          const int row = cf * 16 + l15;
          kF[cf][ks] = *(const bf16x8*)(kb + row * 128 + ((ks * 64 + lg * 16) ^ ((row & 7) << 4)));
        }
      f32x4 sf[4] = {};
      __builtin_amdgcn_s_setprio(1);
#pragma unroll
      for (int cf = 0; cf < 4; cf++)
#pragma unroll
        for (int ks = 0; ks < 2; ks++)
          sf[cf] = __builtin_amdgcn_mfma_f32_16x16x32_bf16(qf[ks], kF[cf][ks], sf[cf], 0, 0, 0);
      __builtin_amdgcn_s_setprio(0);

      const int kv0 = it * 64;
      const bool need_mask = (it == nt - 1);
#pragma unroll
      for (int reg = 0; reg < 4; reg++) {
        float a[4];
#pragma unroll
        for (int cf = 0; cf < 4; cf++) a[cf] = sf[cf][reg] * 0.125f;
        if (need_mask) {
          const int qrow = qb + lg * 4 + reg;
#pragma unroll
          for (int cf = 0; cf < 4; cf++)
            if (kv0 + cf * 16 + l15 > qrow) a[cf] = -1e30f;
        }
        float mx = fmaxf(fmaxf(a[0], a[1]), fmaxf(a[2], a[3]));
#pragma unroll
        for (int dd = 1; dd < 16; dd <<= 1) mx = fmaxf(mx, __shfl_xor(mx, dd));
        const float mnew = fmaxf(mrow[reg], mx);
        const float alpha = __expf(mrow[reg] - mnew);
        float p[4], rs = 0.f;
#pragma unroll
        for (int cf = 0; cf < 4; cf++) { p[cf] = __expf(a[cf] - mnew); rs += p[cf]; }
#pragma unroll
        for (int dd = 1; dd < 16; dd <<= 1) rs += __shfl_xor(rs, dd);
        mrow[reg] = mnew;
        lsum[reg] = lsum[reg] * alpha + rs;
#pragma unroll
        for (int cf = 0; cf < 4; cf++) acc[cf][reg] *= alpha;
        const int prow = lg * 4 + reg;
#pragma unroll
        for (int cf = 0; cf < 4; cf++) Ps[w][prow][cf * 16 + l15] = (bf16_t)p[cf];
      }

      asm volatile("s_waitcnt lgkmcnt(0)" ::: "memory");  // Ps writes visible (wave-local)

      bf16x8 pf[2], vf[4][2];
#pragma unroll
      for (int ks = 0; ks < 2; ks++)
        pf[ks] = *(const bf16x8*)(&Ps[w][l15][ks * 32 + lg * 8]);
#pragma unroll
      for (int cf = 0; cf < 4; cf++)
#pragma unroll
        for (int ks = 0; ks < 2; ks++) {
          const int row = cf * 16 + l15;
          vf[cf][ks] = *(const bf16x8*)(vb + row * 128 + ((ks * 64 + lg * 16) ^ ((row & 7) << 4)));
        }
      __builtin_amdgcn_s_setprio(1);
#pragma unroll
      for (int cf = 0; cf < 4; cf++)
#pragma unroll
        for (int ks = 0; ks < 2; ks++)
          acc[cf] = __builtin_amdgcn_mfma_f32_16x16x32_bf16(pf[ks], vf[cf][ks], acc[cf], 0, 0, 0);
      __builtin_amdgcn_s_setprio(0);

      __syncthreads();   // vmcnt(0)+barrier: next tile landed, all waves done with cur
      cur ^= 1;
    }

#pragma unroll
    for (int reg = 0; reg < 4; reg++) {
      const float inv = 1.0f / lsum[reg];
      const int t = qb + lg * 4 + reg;
#pragma unroll
      for (int cf = 0; cf < 4; cf++) {
        const float v = acc[cf][reg] * inv;
        am = fmaxf(am, fabsf(v));
        Out[(size_t)(b * 2048 + t) * 1024 + h * 64 + cf * 16 + l15] = v;
      }
    }
  }
#undef STAGE

#pragma unroll
  for (int dd = 1; dd < 64; dd <<= 1) am = fmaxf(am, __shfl_xor(am, dd));
  if (lane == 0) atomicMax((int*)amax_out, __float_as_int(am));
}

// ---------------- host ----------------
extern "C" void kernel_launch(void* const* d_in, const int* in_sizes, int n_in,
                              void* d_out, int out_size, void* d_ws, size_t ws_size,
                              hipStream_t stream) {
  const float* x = (const float*)d_in[0];
  const float* Wqkv = (const float*)d_in[1];
  const float* bqkv = (const float*)d_in[2];
  const float* Wproj = (const float*)d_in[3];
  const float* bproj = (const float*)d_in[4];
  float* out = (float*)d_out;

  char* ws = (char*)d_ws;
  float* amax = (float*)ws;                                  // 4 floats
  int8_t* xq = (int8_t*)(ws + 256);                          // 4 MB
  int8_t* wqq = xq + (size_t)4096 * 1024;                    // 3 MB
  int8_t* wpq = wqq + (size_t)3072 * 1024;                   // 1 MB
  bf16_t* qkv = (bf16_t*)(ws + 8388864);                     // Q | K | VT, 3 x 8 MB bf16
  bf16_t* Q = qkv;
  bf16_t* Kk = qkv + (size_t)32 * 2048 * 64;
  bf16_t* VT = qkv + (size_t)2 * 32 * 2048 * 64;
  float* aout = (float*)(ws + 33554688);                     // 16 MB fp32 attn out
  bf16_t* vtmp = (bf16_t*)aout;                              // 8 MB bf16, dead before attn writes
  int8_t* outq = (int8_t*)(ws + 50331904);                   // 4 MB

  hipMemsetAsync(amax, 0, 16, stream);
  amax_kernel<<<512, 256, 0, stream>>>(x, 4194304, amax + 0);
  amax_kernel<<<512, 256, 0, stream>>>(Wqkv, 3145728, amax + 1);
  amax_kernel<<<256, 256, 0, stream>>>(Wproj, 1048576, amax + 2);
  quant_kernel<<<512, 256, 0, stream>>>(x, 4194304, amax + 0, xq);
  quant_kernel<<<512, 256, 0, stream>>>(Wqkv, 3145728, amax + 1, wqq);
  quant_kernel<<<256, 256, 0, stream>>>(Wproj, 1048576, amax + 2, wpq);
  gemm_i8_kernel<0><<<dim3(24, 32), 256, 0, stream>>>(xq, wqq, amax + 0, amax + 1, bqkv,
                                                      qkv, vtmp, nullptr);
  transpose_v_kernel<<<dim3(32, 32), 256, 0, stream>>>(vtmp, VT);
  attn_kernel<<<dim3(32, 16), 256, 0, stream>>>(Q, Kk, VT, aout, amax + 3);
  quant_kernel<<<512, 256, 0, stream>>>(aout, 4194304, amax + 3, outq);
  gemm_i8_kernel<1><<<dim3(8, 32), 256, 0, stream>>>(outq, wpq, amax + 3, amax + 2, bproj,
                                                     nullptr, nullptr, out);
}

// Round 3
// 156.529 us; speedup vs baseline: 1.4475x; 1.1502x over previous
//
#include <hip/hip_runtime.h>
#include <hip/hip_bf16.h>
#include <stdint.h>

typedef __bf16 bf16_t;
typedef bf16_t bf16x4 __attribute__((ext_vector_type(4)));
typedef bf16_t bf16x8 __attribute__((ext_vector_type(8)));
typedef int i32x4 __attribute__((ext_vector_type(4)));
typedef float f32x4 __attribute__((ext_vector_type(4)));

#define QMAXF 127.0f

// async global->LDS, 16B per lane. HW uses wave-uniform LDS base + lane*16;
// passing base+lane*16 matches (lane 0 defines the base).
__device__ __forceinline__ void gl16(const void* g, void* l) {
  __builtin_amdgcn_global_load_lds(
      (__attribute__((address_space(1))) void*)(g),
      (__attribute__((address_space(3))) void*)(l), 16, 0, 0);
}

// ---------------- fused 3-tensor amax ----------------
__global__ __launch_bounds__(256) void amax3_kernel(const float* __restrict__ p0, int n0,
                                                    const float* __restrict__ p1, int n1,
                                                    const float* __restrict__ p2, int n2,
                                                    float* __restrict__ dst) {
  const float* p; int n; float* d; int b0, nb;
  if (blockIdx.x < 512)      { p = p0; n = n0; d = dst + 0; b0 = 0;   nb = 512; }
  else if (blockIdx.x < 768) { p = p1; n = n1; d = dst + 1; b0 = 512; nb = 256; }
  else                       { p = p2; n = n2; d = dst + 2; b0 = 768; nb = 128; }
  const int n4 = n >> 2;
  const int stride = nb * 256;
  float m = 0.f;
  for (int i = (blockIdx.x - b0) * 256 + threadIdx.x; i < n4; i += stride) {
    const f32x4 v = ((const f32x4*)p)[i];
    m = fmaxf(m, fmaxf(fmaxf(fabsf(v[0]), fabsf(v[1])), fmaxf(fabsf(v[2]), fabsf(v[3]))));
  }
#pragma unroll
  for (int dd = 1; dd < 64; dd <<= 1) m = fmaxf(m, __shfl_xor(m, dd));
  __shared__ float sm[4];
  if ((threadIdx.x & 63) == 0) sm[threadIdx.x >> 6] = m;
  __syncthreads();
  if (threadIdx.x == 0) {
    float mm = fmaxf(fmaxf(sm[0], sm[1]), fmaxf(sm[2], sm[3]));
    atomicMax((int*)d, __float_as_int(mm));  // valid: values >= 0
  }
}

// ---------------- int8 quantize: clip(round(x/s),-127,127) ----------------
__device__ __forceinline__ void quant_body(const float* __restrict__ p, int n,
                                           const float* __restrict__ amax,
                                           int8_t* __restrict__ q, int bid, int nb) {
  const float s = fmaxf(amax[0] / QMAXF, 1e-8f);
  const int n4 = n >> 2;
  const int stride = nb * 256;
  for (int i = bid * 256 + (int)threadIdx.x; i < n4; i += stride) {
    const f32x4 v = ((const f32x4*)p)[i];
    int r[4];
#pragma unroll
    for (int j = 0; j < 4; j++) {
      float t = rintf(v[j] / s);               // RNE == jnp.round
      t = fminf(127.f, fmaxf(-127.f, t));
      r[j] = (int)t;
    }
    ((uint32_t*)q)[i] = (uint32_t)(r[0] & 0xff) | ((uint32_t)(r[1] & 0xff) << 8) |
                        ((uint32_t)(r[2] & 0xff) << 16) | ((uint32_t)(r[3] & 0xff) << 24);
  }
}

__global__ __launch_bounds__(256) void quant3_kernel(const float* __restrict__ p0, int n0,
                                                     const float* __restrict__ p1, int n1,
                                                     const float* __restrict__ p2, int n2,
                                                     const float* __restrict__ amax,
                                                     int8_t* __restrict__ q0,
                                                     int8_t* __restrict__ q1,
                                                     int8_t* __restrict__ q2) {
  if (blockIdx.x < 512)      quant_body(p0, n0, amax + 0, q0, blockIdx.x, 512);
  else if (blockIdx.x < 768) quant_body(p1, n1, amax + 1, q1, blockIdx.x - 512, 256);
  else                       quant_body(p2, n2, amax + 2, q2, blockIdx.x - 768, 128);
}

__global__ __launch_bounds__(256) void quant_kernel(const float* __restrict__ p, int n,
                                                    const float* __restrict__ amax,
                                                    int8_t* __restrict__ q) {
  quant_body(p, n, amax, q, blockIdx.x, gridDim.x);
}

// ---------------- int8 GEMM: out[M,N] = A[M,K] * Bw[N,K]^T, K=1024 ----------------
template <int MODE>
__global__ __launch_bounds__(256) void gemm_i8_kernel(
    const int8_t* __restrict__ A, const int8_t* __restrict__ Bw,
    const float* __restrict__ amaxA, const float* __restrict__ amaxB,
    const float* __restrict__ bias,
    bf16_t* __restrict__ qkv_out, bf16_t* __restrict__ vtmp, float* __restrict__ f_out) {
  constexpr int K = 1024;
  __shared__ int8_t As[128 * 64];
  __shared__ int8_t Bs[128 * 64];
  const int tid = threadIdx.x;
  const int lane = tid & 63;
  const int w = tid >> 6, wr = w >> 1, wc = w & 1;
  const int l15 = lane & 15, lg = lane >> 4;
  const int bm = blockIdx.y * 128, bn = blockIdx.x * 128;

  const int sr = tid >> 2;
  const int sc = (tid & 3) * 16;
  const int8_t* gA = A + (size_t)(bm + sr) * K + sc;
  const int8_t* gB = Bw + (size_t)(bn + sr) * K + sc;
  int8_t* lA = As + tid * 16;
  int8_t* lB = Bs + tid * 16;

  i32x4 acc[4][4] = {};

  for (int k0 = 0; k0 < K; k0 += 64) {
    __syncthreads();
    gl16(gA + k0, lA);
    gl16(gA + 64 * K + k0, lA + 4096);
    gl16(gB + k0, lB);
    gl16(gB + 64 * K + k0, lB + 4096);
    __syncthreads();
    i32x4 aF[4], bF[4];
#pragma unroll
    for (int m = 0; m < 4; m++)
      aF[m] = *(const i32x4*)(As + (wr * 64 + m * 16 + l15) * 64 + lg * 16);
#pragma unroll
    for (int n = 0; n < 4; n++)
      bF[n] = *(const i32x4*)(Bs + (wc * 64 + n * 16 + l15) * 64 + lg * 16);
#pragma unroll
    for (int m = 0; m < 4; m++)
#pragma unroll
      for (int n = 0; n < 4; n++)
        acc[m][n] = __builtin_amdgcn_mfma_i32_16x16x64_i8(aF[m], bF[n], acc[m][n], 0, 0, 0);
  }

  const float sA = fmaxf(amaxA[0] / QMAXF, 1e-8f);
  const float sB = fmaxf(amaxB[0] / QMAXF, 1e-8f);
  const float s = sA * sB;

#pragma unroll
  for (int m = 0; m < 4; m++) {
#pragma unroll
    for (int n = 0; n < 4; n++) {
      const int c = bn + wc * 64 + n * 16 + l15;
      const float bs = bias[c];
#pragma unroll
      for (int reg = 0; reg < 4; reg++) {
        const int r = bm + wr * 64 + m * 16 + lg * 4 + reg;
        const float v = (float)acc[m][n][reg] * s + bs;
        if (MODE == 0) {
          const int which = c >> 10, hd = c & 1023;
          const int b = r >> 11, t = r & 2047;
          const size_t idx = (size_t)((((b << 4) + (hd >> 6)) * 2048 + t) << 6) + (hd & 63);
          if (which < 2)
            qkv_out[(size_t)which * (32u * 2048 * 64) + idx] = (bf16_t)v;
          else
            vtmp[idx] = (bf16_t)v;
        } else {
          f_out[(size_t)r * 1024 + c] = v;
        }
      }
    }
  }
}

// ---------------- V transpose: [BH][2048][64] -> [BH][64][2048] ----------------
__global__ __launch_bounds__(256) void transpose_v_kernel(const bf16_t* __restrict__ Vin,
                                                          bf16_t* __restrict__ VT) {
  __shared__ bf16_t L[64][72];
  const int bh = blockIdx.y;
  const int t0 = blockIdx.x * 64;
  const int tid = threadIdx.x;
  const bf16_t* src = Vin + ((size_t)bh * 2048 + t0) * 64;
  {
    const int r = tid >> 3, c = (tid & 7) * 8;
    *(bf16x8*)&L[r][c] = *(const bf16x8*)(src + (size_t)r * 64 + c);
    *(bf16x8*)&L[r + 32][c] = *(const bf16x8*)(src + (size_t)(r + 32) * 64 + c);
  }
  __syncthreads();
  bf16_t* dst = VT + (size_t)bh * 64 * 2048 + t0;
  const int d = tid >> 2, c0 = (tid & 3) * 16;
  bf16_t tmp[16];
#pragma unroll
  for (int j = 0; j < 16; j++) tmp[j] = L[c0 + j][d];
  *(bf16x8*)(dst + (size_t)d * 2048 + c0) = *(bf16x8*)(&tmp[0]);
  *(bf16x8*)(dst + (size_t)d * 2048 + c0 + 8) = *(bf16x8*)(&tmp[8]);
}

// ---------------- causal flash attention: 1-wave blocks, counted vmcnt ----------------
// grid (32 bh, 64 pairs), block = 64 threads (1 wave).
// Block handles 16-row q-tiles {p, 127-p}: exactly 33 KV-iters (KVBLK=64) per block.
// Swapped QK^T: lane owns q-row (q = qb + l15); k in-lane = rf*16 + lg*4 + reg.
__global__ __launch_bounds__(64) void attn_kernel(
    const bf16_t* __restrict__ Qg, const bf16_t* __restrict__ Kg, const bf16_t* __restrict__ VTg,
    float* __restrict__ Out, float* __restrict__ amax_out) {
  const int bh = blockIdx.x;            // fastest-varying -> bh%8 pins XCD (L2 locality)
  const int pair = blockIdx.y;
  const int lane = threadIdx.x;
  const int l15 = lane & 15, lg = lane >> 4;
  const int b = bh >> 4, h = bh & 15;

  const bf16_t* Qp = Qg + (size_t)bh * 2048 * 64;
  const char* Kbase = (const char*)(Kg + (size_t)bh * 2048 * 64);
  const char* Vbase = (const char*)(VTg + (size_t)bh * 64 * 2048);

  __shared__ bf16_t Kb[64 * 64];   // [kv][d] 8KB, swizzled content, single-buffered
  __shared__ bf16_t Vb[64 * 64];   // [d][kv] 8KB, swizzled content, single-buffered
  __shared__ bf16_t Ps[16][72];    // [q][k] P tile

  float am = 0.f;

  // 8 x gl16 (1KB each); swizzle via per-lane global source, LDS linear
  auto stageK = [&](int kv0) {
#pragma unroll
    for (int i = 0; i < 8; i++) {
      const int o = i * 1024 + lane * 16;
      const int row = o >> 7;
      const int sbc = (o & 127) ^ ((row & 7) << 4);
      gl16(Kbase + (size_t)(kv0 + row) * 128 + sbc, (char*)Kb + o);
    }
  };
  auto stageV = [&](int kv0) {
#pragma unroll
    for (int i = 0; i < 8; i++) {
      const int o = i * 1024 + lane * 16;
      const int row = o >> 7;
      const int sbc = (o & 127) ^ ((row & 7) << 4);
      gl16(Vbase + (size_t)row * 4096 + (size_t)kv0 * 2 + sbc, (char*)Vb + o);
    }
  };

  for (int half = 0; half < 2; ++half) {
    const int tile = half ? (127 - pair) : pair;
    const int qb = tile * 16;
    const int nt = (tile >> 2) + 1;
    const int qrow = qb + l15;

    bf16x8 qf[2];
#pragma unroll
    for (int ks = 0; ks < 2; ks++)
      qf[ks] = *(const bf16x8*)(Qp + (size_t)(qb + l15) * 64 + ks * 32 + lg * 8);

    f32x4 acc[4] = {};
    float mrow = -1e30f, lsum = 0.f;

    stageK(0);   // 8 outstanding
    stageV(0);   // 16 outstanding

    for (int it = 0; it < nt; ++it) {
      const int kv0 = it * 64;

      // K_it landed (V_it's 8 remain in flight)
      asm volatile("s_waitcnt vmcnt(8)" ::: "memory");
      __builtin_amdgcn_sched_barrier(0);

      bf16x8 kF[4][2];
#pragma unroll
      for (int rf = 0; rf < 4; rf++)
#pragma unroll
        for (int ks = 0; ks < 2; ks++) {
          const int row = rf * 16 + l15;
          kF[rf][ks] = *(const bf16x8*)((const char*)Kb + row * 128 +
                                        ((ks * 64 + lg * 16) ^ ((row & 7) << 4)));
        }
      // K fragments now requested; ensure they are in VGPRs before next-tile K overwrites
      asm volatile("s_waitcnt lgkmcnt(0)" ::: "memory");
      __builtin_amdgcn_sched_barrier(0);
      if (it + 1 < nt) stageK(kv0 + 64);

      f32x4 sfT[4] = {};
      __builtin_amdgcn_s_setprio(1);
#pragma unroll
      for (int rf = 0; rf < 4; rf++)
#pragma unroll
        for (int ks = 0; ks < 2; ks++)
          sfT[rf] = __builtin_amdgcn_mfma_f32_16x16x32_bf16(kF[rf][ks], qf[ks], sfT[rf], 0, 0, 0);
      __builtin_amdgcn_s_setprio(0);

      // in-lane softmax over this lane's 16 k-values
      float a[16];
      const bool need_mask = (it == nt - 1);
#pragma unroll
      for (int rf = 0; rf < 4; rf++)
#pragma unroll
        for (int reg = 0; reg < 4; reg++) {
          float v = sfT[rf][reg] * 0.125f;
          if (need_mask && (kv0 + rf * 16 + lg * 4 + reg > qrow)) v = -1e30f;
          a[rf * 4 + reg] = v;
        }
      float mx = a[0];
#pragma unroll
      for (int i = 1; i < 16; i++) mx = fmaxf(mx, a[i]);
      mx = fmaxf(mx, __shfl_xor(mx, 16));
      mx = fmaxf(mx, __shfl_xor(mx, 32));

      if (!__all(mx <= mrow + 8.f)) {   // defer-max: rescale only on real max growth
        const float mnew = fmaxf(mrow, mx);
        const float alpha = __expf(mrow - mnew);
        float av[4];
#pragma unroll
        for (int reg = 0; reg < 4; reg++) av[reg] = __shfl(alpha, lg * 4 + reg);
#pragma unroll
        for (int cf = 0; cf < 4; cf++)
#pragma unroll
          for (int reg = 0; reg < 4; reg++) acc[cf][reg] *= av[reg];
        lsum *= alpha;
        mrow = mnew;
      }

      float p[16], rs = 0.f;
#pragma unroll
      for (int i = 0; i < 16; i++) { p[i] = __expf(a[i] - mrow); rs += p[i]; }
      rs += __shfl_xor(rs, 16);
      rs += __shfl_xor(rs, 32);
      lsum += rs;

#pragma unroll
      for (int rf = 0; rf < 4; rf++) {
        bf16x4 pk;
#pragma unroll
        for (int reg = 0; reg < 4; reg++) pk[reg] = (bf16_t)p[rf * 4 + reg];
        *(bf16x4*)(&Ps[l15][rf * 16 + lg * 4]) = pk;
      }

      // V_it landed (K_{it+1}'s 8 may remain in flight)
      if (it + 1 < nt) {
        asm volatile("s_waitcnt vmcnt(8)" ::: "memory");
      } else {
        asm volatile("s_waitcnt vmcnt(0)" ::: "memory");
      }
      __builtin_amdgcn_sched_barrier(0);

      bf16x8 pf[2], vf[4][2];
#pragma unroll
      for (int ks = 0; ks < 2; ks++)
        pf[ks] = *(const bf16x8*)(&Ps[l15][ks * 32 + lg * 8]);
#pragma unroll
      for (int cf = 0; cf < 4; cf++)
#pragma unroll
        for (int ks = 0; ks < 2; ks++) {
          const int row = cf * 16 + l15;
          vf[cf][ks] = *(const bf16x8*)((const char*)Vb + row * 128 +
                                        ((ks * 64 + lg * 16) ^ ((row & 7) << 4)));
        }
      // V/P fragments in VGPRs before next-tile V overwrites
      asm volatile("s_waitcnt lgkmcnt(0)" ::: "memory");
      __builtin_amdgcn_sched_barrier(0);
      if (it + 1 < nt) stageV(kv0 + 64);

      __builtin_amdgcn_s_setprio(1);
#pragma unroll
      for (int cf = 0; cf < 4; cf++)
#pragma unroll
        for (int ks = 0; ks < 2; ks++)
          acc[cf] = __builtin_amdgcn_mfma_f32_16x16x32_bf16(pf[ks], vf[cf][ks], acc[cf], 0, 0, 0);
      __builtin_amdgcn_s_setprio(0);
    }

    const float inv = 1.0f / lsum;
    float iq[4];
#pragma unroll
    for (int reg = 0; reg < 4; reg++) iq[reg] = __shfl(inv, lg * 4 + reg);
#pragma unroll
    for (int cf = 0; cf < 4; cf++)
#pragma unroll
      for (int reg = 0; reg < 4; reg++) {
        const float v = acc[cf][reg] * iq[reg];
        am = fmaxf(am, fabsf(v));
        const int t = qb + lg * 4 + reg;
        Out[(size_t)(b * 2048 + t) * 1024 + h * 64 + cf * 16 + l15] = v;
      }
  }

#pragma unroll
  for (int dd = 1; dd < 64; dd <<= 1) am = fmaxf(am, __shfl_xor(am, dd));
  if (lane == 0) atomicMax((int*)amax_out, __float_as_int(am));
}

// ---------------- host ----------------
extern "C" void kernel_launch(void* const* d_in, const int* in_sizes, int n_in,
                              void* d_out, int out_size, void* d_ws, size_t ws_size,
                              hipStream_t stream) {
  const float* x = (const float*)d_in[0];
  const float* Wqkv = (const float*)d_in[1];
  const float* bqkv = (const float*)d_in[2];
  const float* Wproj = (const float*)d_in[3];
  const float* bproj = (const float*)d_in[4];
  float* out = (float*)d_out;

  char* ws = (char*)d_ws;
  float* amax = (float*)ws;                                  // 4 floats
  int8_t* xq = (int8_t*)(ws + 256);                          // 4 MB
  int8_t* wqq = xq + (size_t)4096 * 1024;                    // 3 MB
  int8_t* wpq = wqq + (size_t)3072 * 1024;                   // 1 MB
  bf16_t* qkv = (bf16_t*)(ws + 8388864);                     // Q | K | VT, 3 x 8 MB bf16
  bf16_t* Q = qkv;
  bf16_t* Kk = qkv + (size_t)32 * 2048 * 64;
  bf16_t* VT = qkv + (size_t)2 * 32 * 2048 * 64;
  float* aout = (float*)(ws + 33554688);                     // 16 MB fp32 attn out
  bf16_t* vtmp = (bf16_t*)aout;                              // 8 MB bf16, dead before attn writes
  int8_t* outq = (int8_t*)(ws + 50331904);                   // 4 MB

  hipMemsetAsync(amax, 0, 16, stream);
  amax3_kernel<<<896, 256, 0, stream>>>(x, 4194304, Wqkv, 3145728, Wproj, 1048576, amax);
  quant3_kernel<<<896, 256, 0, stream>>>(x, 4194304, Wqkv, 3145728, Wproj, 1048576, amax,
                                         xq, wqq, wpq);
  gemm_i8_kernel<0><<<dim3(24, 32), 256, 0, stream>>>(xq, wqq, amax + 0, amax + 1, bqkv,
                                                      qkv, vtmp, nullptr);
  transpose_v_kernel<<<dim3(32, 32), 256, 0, stream>>>(vtmp, VT);
  attn_kernel<<<dim3(32, 64), 64, 0, stream>>>(Q, Kk, VT, aout, amax + 3);
  quant_kernel<<<512, 256, 0, stream>>>(aout, 4194304, amax + 3, outq);
  gemm_i8_kernel<1><<<dim3(8, 32), 256, 0, stream>>>(outq, wpq, amax + 3, amax + 2, bproj,
                                                     nullptr, nullptr, out);
}

// Round 4
// 144.412 us; speedup vs baseline: 1.5689x; 1.0839x over previous
//
#include <hip/hip_runtime.h>
#include <hip/hip_bf16.h>
#include <stdint.h>

typedef __bf16 bf16_t;
typedef bf16_t bf16x4 __attribute__((ext_vector_type(4)));
typedef bf16_t bf16x8 __attribute__((ext_vector_type(8)));
typedef short s16x4 __attribute__((ext_vector_type(4)));
typedef int i32x4 __attribute__((ext_vector_type(4)));
typedef float f32x4 __attribute__((ext_vector_type(4)));

#define QMAXF 127.0f

// async global->LDS, 16B per lane. LDS dest is wave-uniform base + lane*16.
__device__ __forceinline__ void gl16(const void* g, void* l) {
  __builtin_amdgcn_global_load_lds(
      (__attribute__((address_space(1))) void*)(g),
      (__attribute__((address_space(3))) void*)(l), 16, 0, 0);
}

// ---------------- fused 3-tensor amax ----------------
__global__ __launch_bounds__(256) void amax3_kernel(const float* __restrict__ p0, int n0,
                                                    const float* __restrict__ p1, int n1,
                                                    const float* __restrict__ p2, int n2,
                                                    float* __restrict__ dst) {
  const float* p; int n; float* d; int b0, nb;
  if (blockIdx.x < 512)      { p = p0; n = n0; d = dst + 0; b0 = 0;   nb = 512; }
  else if (blockIdx.x < 768) { p = p1; n = n1; d = dst + 1; b0 = 512; nb = 256; }
  else                       { p = p2; n = n2; d = dst + 2; b0 = 768; nb = 128; }
  const int n4 = n >> 2;
  const int stride = nb * 256;
  float m = 0.f;
  for (int i = (blockIdx.x - b0) * 256 + threadIdx.x; i < n4; i += stride) {
    const f32x4 v = ((const f32x4*)p)[i];
    m = fmaxf(m, fmaxf(fmaxf(fabsf(v[0]), fabsf(v[1])), fmaxf(fabsf(v[2]), fabsf(v[3]))));
  }
#pragma unroll
  for (int dd = 1; dd < 64; dd <<= 1) m = fmaxf(m, __shfl_xor(m, dd));
  __shared__ float sm[4];
  if ((threadIdx.x & 63) == 0) sm[threadIdx.x >> 6] = m;
  __syncthreads();
  if (threadIdx.x == 0) {
    float mm = fmaxf(fmaxf(sm[0], sm[1]), fmaxf(sm[2], sm[3]));
    atomicMax((int*)d, __float_as_int(mm));  // valid: values >= 0
  }
}

// ---------------- int8 quantize: clip(round(x/s),-127,127) ----------------
__device__ __forceinline__ void quant_body(const float* __restrict__ p, int n,
                                           const float* __restrict__ amax,
                                           int8_t* __restrict__ q, int bid, int nb) {
  const float s = fmaxf(amax[0] / QMAXF, 1e-8f);
  const int n4 = n >> 2;
  const int stride = nb * 256;
  for (int i = bid * 256 + (int)threadIdx.x; i < n4; i += stride) {
    const f32x4 v = ((const f32x4*)p)[i];
    int r[4];
#pragma unroll
    for (int j = 0; j < 4; j++) {
      float t = rintf(v[j] / s);               // RNE == jnp.round
      t = fminf(127.f, fmaxf(-127.f, t));
      r[j] = (int)t;
    }
    ((uint32_t*)q)[i] = (uint32_t)(r[0] & 0xff) | ((uint32_t)(r[1] & 0xff) << 8) |
                        ((uint32_t)(r[2] & 0xff) << 16) | ((uint32_t)(r[3] & 0xff) << 24);
  }
}

__global__ __launch_bounds__(256) void quant3_kernel(const float* __restrict__ p0, int n0,
                                                     const float* __restrict__ p1, int n1,
                                                     const float* __restrict__ p2, int n2,
                                                     const float* __restrict__ amax,
                                                     int8_t* __restrict__ q0,
                                                     int8_t* __restrict__ q1,
                                                     int8_t* __restrict__ q2) {
  if (blockIdx.x < 512)      quant_body(p0, n0, amax + 0, q0, blockIdx.x, 512);
  else if (blockIdx.x < 768) quant_body(p1, n1, amax + 1, q1, blockIdx.x - 512, 256);
  else                       quant_body(p2, n2, amax + 2, q2, blockIdx.x - 768, 128);
}

__global__ __launch_bounds__(256) void quant_kernel(const float* __restrict__ p, int n,
                                                    const float* __restrict__ amax,
                                                    int8_t* __restrict__ q) {
  quant_body(p, n, amax, q, blockIdx.x, gridDim.x);
}

// ---------------- int8 GEMM: out[M,N] = A[M,K] * Bw[N,K]^T, K=1024 ----------------
// MODE 0: dequant+bias; Q,K -> bf16 [which][BH][T][D]; V -> bf16 V^T [BH][D][T]  (N=3072)
// MODE 1: dequant+bias, write fp32 row-major [M,1024]                            (N=1024)
template <int MODE>
__global__ __launch_bounds__(256) void gemm_i8_kernel(
    const int8_t* __restrict__ A, const int8_t* __restrict__ Bw,
    const float* __restrict__ amaxA, const float* __restrict__ amaxB,
    const float* __restrict__ bias,
    bf16_t* __restrict__ qkv_out, bf16_t* __restrict__ vt_out, float* __restrict__ f_out) {
  constexpr int K = 1024;
  __shared__ int8_t As[128 * 64];
  __shared__ int8_t Bs[128 * 64];
  const int tid = threadIdx.x;
  const int lane = tid & 63;
  const int w = tid >> 6, wr = w >> 1, wc = w & 1;
  const int l15 = lane & 15, lg = lane >> 4;
  const int bm = blockIdx.y * 128, bn = blockIdx.x * 128;

  const int sr = tid >> 2;
  const int sc = (tid & 3) * 16;
  const int8_t* gA = A + (size_t)(bm + sr) * K + sc;
  const int8_t* gB = Bw + (size_t)(bn + sr) * K + sc;
  int8_t* lA = As + tid * 16;
  int8_t* lB = Bs + tid * 16;

  i32x4 acc[4][4] = {};

  for (int k0 = 0; k0 < K; k0 += 64) {
    __syncthreads();
    gl16(gA + k0, lA);
    gl16(gA + 64 * K + k0, lA + 4096);
    gl16(gB + k0, lB);
    gl16(gB + 64 * K + k0, lB + 4096);
    __syncthreads();
    i32x4 aF[4], bF[4];
#pragma unroll
    for (int m = 0; m < 4; m++)
      aF[m] = *(const i32x4*)(As + (wr * 64 + m * 16 + l15) * 64 + lg * 16);
#pragma unroll
    for (int n = 0; n < 4; n++)
      bF[n] = *(const i32x4*)(Bs + (wc * 64 + n * 16 + l15) * 64 + lg * 16);
#pragma unroll
    for (int m = 0; m < 4; m++)
#pragma unroll
      for (int n = 0; n < 4; n++)
        acc[m][n] = __builtin_amdgcn_mfma_i32_16x16x64_i8(aF[m], bF[n], acc[m][n], 0, 0, 0);
  }

  const float sA = fmaxf(amaxA[0] / QMAXF, 1e-8f);
  const float sB = fmaxf(amaxB[0] / QMAXF, 1e-8f);
  const float s = sA * sB;

#pragma unroll
  for (int m = 0; m < 4; m++) {
#pragma unroll
    for (int n = 0; n < 4; n++) {
      const int c = bn + wc * 64 + n * 16 + l15;
      const float bs = bias[c];
      const int r0 = bm + wr * 64 + m * 16 + lg * 4;
      float vv[4];
#pragma unroll
      for (int reg = 0; reg < 4; reg++) vv[reg] = (float)acc[m][n][reg] * s + bs;
      if (MODE == 0) {
        const int which = c >> 10, hd = c & 1023;
        if (which < 2) {
#pragma unroll
          for (int reg = 0; reg < 4; reg++) {
            const int r = r0 + reg;
            const int b = r >> 11, t = r & 2047;
            qkv_out[(size_t)which * (32u * 2048 * 64) +
                    (size_t)((((b << 4) + (hd >> 6)) * 2048 + t) << 6) + (hd & 63)] = (bf16_t)vv[reg];
          }
        } else {
          // V^T [BH][D=64][T=2048], t contiguous within the 4 regs -> vector store
          const int b = r0 >> 11, t0 = r0 & 2047;
          const int h = hd >> 6, d = hd & 63;
          bf16x4 pk;
#pragma unroll
          for (int reg = 0; reg < 4; reg++) pk[reg] = (bf16_t)vv[reg];
          *(bf16x4*)(vt_out + ((size_t)((b << 4) + h) * 64 + d) * 2048 + t0) = pk;
        }
      } else {
#pragma unroll
        for (int reg = 0; reg < 4; reg++) f_out[(size_t)(r0 + reg) * 1024 + c] = vv[reg];
      }
    }
  }
}

// ---------------- causal flash attention ----------------
// grid (32 bh, 32 pairs), block 128 = 2 waves x 16 q-rows (32-row supertile).
// Block handles supertiles {S, 63-S}: exactly 33 KV-iters (KVBLK=64) total.
// Swapped QK^T: lane owns q-row l15; k in-lane = rf*16 + lg*4 + reg.
// PV via 16x16x16 MFMA: P fragments are exactly the lane-local p values (no LDS roundtrip).
__global__ __launch_bounds__(128) void attn_kernel(
    const bf16_t* __restrict__ Qg, const bf16_t* __restrict__ Kg, const bf16_t* __restrict__ VTg,
    float* __restrict__ Out, float* __restrict__ amax_out) {
  const int bh = blockIdx.x;            // fastest-varying -> bh%8 pins XCD (L2 locality)
  const int pairi = blockIdx.y;         // 0..31
  const int tid = threadIdx.x, lane = tid & 63, w = tid >> 6;
  const int l15 = lane & 15, lg = lane >> 4;
  const int b = bh >> 4, h = bh & 15;

  const bf16_t* Qp = Qg + (size_t)bh * 2048 * 64;
  const char* Kbase = (const char*)(Kg + (size_t)bh * 2048 * 64);
  const char* Vbase = (const char*)(VTg + (size_t)bh * 64 * 2048);

  __shared__ __align__(16) bf16_t Kb[2][4096];   // [64 kv][64 d], swizzled content
  __shared__ __align__(16) bf16_t Vb[2][4096];   // [64 d][64 kv], swizzled content

  float am = 0.f;
  const float CSC = 0.18033688f;        // 0.125 * log2(e): softmax in log2 domain

  // wave 0 stages K (8x 1KB), wave 1 stages V (8x 1KB); swizzle via global source
  auto stage = [&](int kv0, int buf) {
#pragma unroll
    for (int i = 0; i < 8; i++) {
      const int o = i * 1024 + lane * 16;
      const int row = o >> 7;
      const int sbc = (o & 127) ^ ((row & 7) << 4);
      if (w == 0)
        gl16(Kbase + (size_t)(kv0 + row) * 128 + sbc, (char*)Kb[buf] + o);
      else
        gl16(Vbase + (size_t)row * 4096 + (size_t)kv0 * 2 + sbc, (char*)Vb[buf] + o);
    }
  };

  for (int half = 0; half < 2; ++half) {
    const int S = half ? (63 - pairi) : pairi;
    const int qb = S * 32 + w * 16;     // this wave's 16 q-rows
    const int nt = (S >> 1) + 1;
    const int qrow = qb + l15;

    bf16x8 qf[2];
#pragma unroll
    for (int ks = 0; ks < 2; ks++)
      qf[ks] = *(const bf16x8*)(Qp + (size_t)(qb + l15) * 64 + ks * 32 + lg * 8);

    f32x4 acc[4] = {};
    float mrow = -1e30f, lsum = 0.f;

    stage(0, 0);
    __syncthreads();                    // drains vmcnt(0): tile 0 landed

    for (int it = 0; it < nt; ++it) {
      const int cur = it & 1;
      const int kv0 = it * 64;
      if (it + 1 < nt) stage(kv0 + 64, cur ^ 1);   // flies across the whole compute phase

      bf16x8 kF[4][2];
#pragma unroll
      for (int rf = 0; rf < 4; rf++)
#pragma unroll
        for (int ks = 0; ks < 2; ks++) {
          const int row = rf * 16 + l15;
          kF[rf][ks] = *(const bf16x8*)((const char*)Kb[cur] + row * 128 +
                                        ((ks * 64 + lg * 16) ^ ((row & 7) << 4)));
        }
      f32x4 sfT[4] = {};
      __builtin_amdgcn_s_setprio(1);
#pragma unroll
      for (int rf = 0; rf < 4; rf++)
#pragma unroll
        for (int ks = 0; ks < 2; ks++)
          sfT[rf] = __builtin_amdgcn_mfma_f32_16x16x32_bf16(kF[rf][ks], qf[ks], sfT[rf], 0, 0, 0);
      __builtin_amdgcn_s_setprio(0);

      // V B-frags for 16x16x16 PV (independent of QK result; latency hides under softmax)
      s16x4 vB[4][4];
#pragma unroll
      for (int cf = 0; cf < 4; cf++)
#pragma unroll
        for (int rf = 0; rf < 4; rf++) {
          const int row = cf * 16 + l15;
          vB[cf][rf] = *(const s16x4*)((const char*)Vb[cur] + row * 128 +
                                       (((rf * 32 + lg * 8)) ^ ((row & 7) << 4)));
        }

      // in-lane softmax (log2 domain) over this lane's 16 k-values
      float a[16];
      const bool need_mask = (it == nt - 1);
#pragma unroll
      for (int rf = 0; rf < 4; rf++)
#pragma unroll
        for (int reg = 0; reg < 4; reg++) {
          float v = sfT[rf][reg] * CSC;
          if (need_mask && (kv0 + rf * 16 + lg * 4 + reg > qrow)) v = -1e30f;
          a[rf * 4 + reg] = v;
        }
      float mx = a[0];
#pragma unroll
      for (int i = 1; i < 16; i++) mx = fmaxf(mx, a[i]);
      mx = fmaxf(mx, __shfl_xor(mx, 16));
      mx = fmaxf(mx, __shfl_xor(mx, 32));

      if (!__all(mx <= mrow + 11.5416f)) {   // defer-max (THR = 8 nats in log2)
        const float mnew = fmaxf(mrow, mx);
        const float alpha = __builtin_amdgcn_exp2f(mrow - mnew);
        float av[4];
#pragma unroll
        for (int reg = 0; reg < 4; reg++) av[reg] = __shfl(alpha, lg * 4 + reg);
#pragma unroll
        for (int cf = 0; cf < 4; cf++)
#pragma unroll
          for (int reg = 0; reg < 4; reg++) acc[cf][reg] *= av[reg];
        lsum *= alpha;
        mrow = mnew;
      }

      float p[16], rs = 0.f;
#pragma unroll
      for (int i = 0; i < 16; i++) { p[i] = __builtin_amdgcn_exp2f(a[i] - mrow); rs += p[i]; }
      rs += __shfl_xor(rs, 16);
      rs += __shfl_xor(rs, 32);
      lsum += rs;

      // p -> bf16 A-frags, feed PV directly (no LDS roundtrip)
      s16x4 pa[4];
#pragma unroll
      for (int rf = 0; rf < 4; rf++) {
        bf16x4 t;
#pragma unroll
        for (int reg = 0; reg < 4; reg++) t[reg] = (bf16_t)p[rf * 4 + reg];
        pa[rf] = __builtin_bit_cast(s16x4, t);
      }
      __builtin_amdgcn_s_setprio(1);
#pragma unroll
      for (int cf = 0; cf < 4; cf++)
#pragma unroll
        for (int rf = 0; rf < 4; rf++)
          acc[cf] = __builtin_amdgcn_mfma_f32_16x16x16bf16_1k(pa[rf], vB[cf][rf], acc[cf], 0, 0, 0);
      __builtin_amdgcn_s_setprio(0);

      __syncthreads();   // drains vmcnt(0)+lgkm: next tile landed, both waves done with cur
    }

    const float inv = 1.0f / lsum;
    float iq[4];
#pragma unroll
    for (int reg = 0; reg < 4; reg++) iq[reg] = __shfl(inv, lg * 4 + reg);
#pragma unroll
    for (int cf = 0; cf < 4; cf++)
#pragma unroll
      for (int reg = 0; reg < 4; reg++) {
        const float v = acc[cf][reg] * iq[reg];
        am = fmaxf(am, fabsf(v));
        const int t = qb + lg * 4 + reg;
        Out[(size_t)(b * 2048 + t) * 1024 + h * 64 + cf * 16 + l15] = v;
      }
  }

#pragma unroll
  for (int dd = 1; dd < 64; dd <<= 1) am = fmaxf(am, __shfl_xor(am, dd));
  if (lane == 0) atomicMax((int*)amax_out, __float_as_int(am));
}

// ---------------- host ----------------
extern "C" void kernel_launch(void* const* d_in, const int* in_sizes, int n_in,
                              void* d_out, int out_size, void* d_ws, size_t ws_size,
                              hipStream_t stream) {
  const float* x = (const float*)d_in[0];
  const float* Wqkv = (const float*)d_in[1];
  const float* bqkv = (const float*)d_in[2];
  const float* Wproj = (const float*)d_in[3];
  const float* bproj = (const float*)d_in[4];
  float* out = (float*)d_out;

  char* ws = (char*)d_ws;
  float* amax = (float*)ws;                                  // 4 floats
  int8_t* xq = (int8_t*)(ws + 256);                          // 4 MB
  int8_t* wqq = xq + (size_t)4096 * 1024;                    // 3 MB
  int8_t* wpq = wqq + (size_t)3072 * 1024;                   // 1 MB
  bf16_t* qkv = (bf16_t*)(ws + 8388864);                     // Q | K | VT, 3 x 8 MB bf16
  bf16_t* Q = qkv;
  bf16_t* Kk = qkv + (size_t)32 * 2048 * 64;
  bf16_t* VT = qkv + (size_t)2 * 32 * 2048 * 64;             // [BH][D][T]
  float* aout = (float*)(ws + 33554688);                     // 16 MB fp32 attn out
  int8_t* outq = (int8_t*)(ws + 50331904);                   // 4 MB

  hipMemsetAsync(amax, 0, 16, stream);
  amax3_kernel<<<896, 256, 0, stream>>>(x, 4194304, Wqkv, 3145728, Wproj, 1048576, amax);
  quant3_kernel<<<896, 256, 0, stream>>>(x, 4194304, Wqkv, 3145728, Wproj, 1048576, amax,
                                         xq, wqq, wpq);
  gemm_i8_kernel<0><<<dim3(24, 32), 256, 0, stream>>>(xq, wqq, amax + 0, amax + 1, bqkv,
                                                      qkv, VT, nullptr);
  attn_kernel<<<dim3(32, 32), 128, 0, stream>>>(Q, Kk, VT, aout, amax + 3);
  quant_kernel<<<512, 256, 0, stream>>>(aout, 4194304, amax + 3, outq);
  gemm_i8_kernel<1><<<dim3(8, 32), 256, 0, stream>>>(outq, wpq, amax + 3, amax + 2, bproj,
                                                     nullptr, nullptr, out);
}